// Round 1
// baseline (687.375 us; speedup 1.0000x reference)
//
#include <hip/hip_runtime.h>
#include <hip/hip_bf16.h>
#include <math.h>

// Problem constants
#define Bz 2
#define Tz 512
#define Cz 2048
#define Hh 32
#define DH 64
#define NTOK (Bz * Tz)   // 1024

typedef __hip_bfloat16 bf16;
typedef __attribute__((ext_vector_type(8))) short short8;
typedef __attribute__((ext_vector_type(4))) float f32x4;

// ---------------------------------------------------------------------------
// async global->LDS, 16B per lane. LDS dest must be wave-uniform base;
// lanes land at base + lane*16.
__device__ __forceinline__ void load_lds16(const void* g, void* l) {
  __builtin_amdgcn_global_load_lds(
      (const __attribute__((address_space(1))) unsigned int*)g,
      (__attribute__((address_space(3))) unsigned int*)l,
      16, 0, 0);
}

// ---------------------------------------------------------------------------
// Weight transpose + f32->bf16: Wt[n][k] = (bf16) W[k][n].  z selects weight.
__global__ __launch_bounds__(256) void k_transpose(
    const float* __restrict__ qw, const float* __restrict__ kw,
    const float* __restrict__ vw, const float* __restrict__ ow,
    bf16* __restrict__ qwt, bf16* __restrict__ kwt,
    bf16* __restrict__ vwt, bf16* __restrict__ owt) {
  __shared__ float tile[32][33];
  const float* W;
  bf16* O;
  switch (blockIdx.z) {
    case 0: W = qw; O = qwt; break;
    case 1: W = kw; O = kwt; break;
    case 2: W = vw; O = vwt; break;
    default: W = ow; O = owt; break;
  }
  int bx = blockIdx.x * 32, by = blockIdx.y * 32;
  int tx = threadIdx.x, ty = threadIdx.y;
#pragma unroll
  for (int i = 0; i < 4; i++)
    tile[ty + 8 * i][tx] = W[(size_t)(by + ty + 8 * i) * Cz + bx + tx];
  __syncthreads();
#pragma unroll
  for (int i = 0; i < 4; i++)
    O[(size_t)(bx + ty + 8 * i) * Cz + by + tx] =
        __float2bfloat16(tile[tx][ty + 8 * i]);
}

// ---------------------------------------------------------------------------
// dx = x_{t-1} - x_t (zero pad at t=0);  xxx = x + dx*maa_x
__global__ __launch_bounds__(256) void k_prep(
    const float* __restrict__ x, const float* __restrict__ maa_x,
    float* __restrict__ dx, float* __restrict__ xxx) {
  int i4 = blockIdx.x * 256 + threadIdx.x;  // over 524288 float4
  int row = i4 >> 9;                        // 512 float4 per row
  int t = row & (Tz - 1);
  int c4 = i4 & 511;
  const float4* x4 = (const float4*)x;
  float4 xv = x4[i4];
  float4 xp = make_float4(0.f, 0.f, 0.f, 0.f);
  if (t != 0) xp = x4[i4 - 512];
  float4 mx = ((const float4*)maa_x)[c4];
  float4 d, xx;
  d.x = xp.x - xv.x; d.y = xp.y - xv.y; d.z = xp.z - xv.z; d.w = xp.w - xv.w;
  xx.x = xv.x + d.x * mx.x; xx.y = xv.y + d.y * mx.y;
  xx.z = xv.z + d.z * mx.z; xx.w = xv.w + d.w * mx.w;
  ((float4*)dx)[i4] = d;
  ((float4*)xxx)[i4] = xx;
}

// ---------------------------------------------------------------------------
// mm = tanh(xxx @ maa_w1)   [NTOK,128], 8 tokens per block
__global__ __launch_bounds__(256) void k_mm(
    const float* __restrict__ xxx, const float* __restrict__ w1,
    float* __restrict__ mm) {
  __shared__ float sX[8][64];
  int tid = threadIdx.x;
  int o = tid & 127, tg = tid >> 7;  // 2 token-groups of 4
  int tok0 = blockIdx.x * 8;
  float acc[4] = {0.f, 0.f, 0.f, 0.f};
  for (int kc = 0; kc < Cz; kc += 64) {
#pragma unroll
    for (int u = 0; u < 2; u++) {
      int idx = tid + 256 * u;
      sX[idx >> 6][idx & 63] = xxx[(size_t)(tok0 + (idx >> 6)) * Cz + kc + (idx & 63)];
    }
    __syncthreads();
    for (int c = 0; c < 64; c++) {
      float w = w1[(size_t)(kc + c) * 128 + o];
#pragma unroll
      for (int t = 0; t < 4; t++) acc[t] += w * sX[tg * 4 + t][c];
    }
    __syncthreads();
  }
#pragma unroll
  for (int t = 0; t < 4; t++)
    mm[(size_t)(tok0 + tg * 4 + t) * 128 + o] = tanhf(acc[t]);
}

// ---------------------------------------------------------------------------
// m_r = mm @ maa_w2[r]; fuse xr/xk/xv (bf16) and xw (f32) outputs.
// grid: (NTOK/8, Cz/256), block 256.
__global__ __launch_bounds__(256) void k_mproj(
    const float* __restrict__ mm, const float* __restrict__ w2,
    const float* __restrict__ x, const float* __restrict__ dx,
    const float* __restrict__ maa_r, const float* __restrict__ maa_k,
    const float* __restrict__ maa_v, const float* __restrict__ maa_w,
    bf16* __restrict__ pxr, bf16* __restrict__ pxk,
    bf16* __restrict__ pxv, float* __restrict__ pxw) {
  __shared__ float sM[8][128];
  int tid = threadIdx.x;
  int tok0 = blockIdx.x * 8;
  int c = blockIdx.y * 256 + tid;
#pragma unroll
  for (int u = 0; u < 4; u++) {
    int idx = tid + 256 * u;
    sM[idx >> 7][idx & 127] = mm[(size_t)tok0 * 128 + idx];
  }
  __syncthreads();
  float m_[4][8];
#pragma unroll
  for (int r = 0; r < 4; r++)
#pragma unroll
    for (int t = 0; t < 8; t++) m_[r][t] = 0.f;
#pragma unroll
  for (int r = 0; r < 4; r++) {
    for (int d = 0; d < 32; d++) {
      float w = w2[(size_t)(r * 32 + d) * Cz + c];
#pragma unroll
      for (int t = 0; t < 8; t++) m_[r][t] += w * sM[t][r * 32 + d];
    }
  }
  float mr = maa_r[c], mk = maa_k[c], mv = maa_v[c], mw = maa_w[c];
#pragma unroll
  for (int t = 0; t < 8; t++) {
    size_t idx = (size_t)(tok0 + t) * Cz + c;
    float xval = x[idx], dval = dx[idx];
    pxr[idx] = __float2bfloat16(xval + dval * (mr + m_[0][t]));
    pxk[idx] = __float2bfloat16(xval + dval * (mk + m_[1][t]));
    pxv[idx] = __float2bfloat16(xval + dval * (mv + m_[2][t]));
    pxw[idx] = xval + dval * (mw + m_[3][t]);
  }
}

// ---------------------------------------------------------------------------
// tw = tanh(xw @ td_w1)  [NTOK,64], 8 tokens per block
__global__ __launch_bounds__(256) void k_tdA(
    const float* __restrict__ xw, const float* __restrict__ w1,
    float* __restrict__ tw) {
  __shared__ float sX[8][64];
  int tid = threadIdx.x;
  int o = tid & 63, tg = tid >> 6;  // 4 groups of 2 tokens
  int tok0 = blockIdx.x * 8;
  float acc0 = 0.f, acc1 = 0.f;
  for (int kc = 0; kc < Cz; kc += 64) {
#pragma unroll
    for (int u = 0; u < 2; u++) {
      int idx = tid + 256 * u;
      sX[idx >> 6][idx & 63] = xw[(size_t)(tok0 + (idx >> 6)) * Cz + kc + (idx & 63)];
    }
    __syncthreads();
    for (int cc = 0; cc < 64; cc++) {
      float w = w1[(size_t)(kc + cc) * 64 + o];
      acc0 += w * sX[tg * 2][cc];
      acc1 += w * sX[tg * 2 + 1][cc];
    }
    __syncthreads();
  }
  tw[(size_t)(tok0 + tg * 2) * 64 + o] = tanhf(acc0);
  tw[(size_t)(tok0 + tg * 2 + 1) * 64 + o] = tanhf(acc1);
}

// ---------------------------------------------------------------------------
// w_log = max(-exp(td + tw @ td_w2), -5); g = exp(w_log); ksc = 1-g
// grid: (NTOK/8, Cz/256)
__global__ __launch_bounds__(256) void k_tdB(
    const float* __restrict__ tw, const float* __restrict__ w2,
    const float* __restrict__ td, float* __restrict__ g,
    float* __restrict__ ksc) {
  __shared__ float sT[8][64];
  int tid = threadIdx.x;
  int tok0 = blockIdx.x * 8;
  int c = blockIdx.y * 256 + tid;
#pragma unroll
  for (int u = 0; u < 2; u++) {
    int idx = tid + 256 * u;
    sT[idx >> 6][idx & 63] = tw[(size_t)tok0 * 64 + idx];
  }
  __syncthreads();
  float acc[8];
#pragma unroll
  for (int t = 0; t < 8; t++) acc[t] = 0.f;
  for (int d = 0; d < 64; d++) {
    float w = w2[(size_t)d * Cz + c];
#pragma unroll
    for (int t = 0; t < 8; t++) acc[t] += w * sT[t][d];
  }
  float tdc = td[c];
#pragma unroll
  for (int t = 0; t < 8; t++) {
    float wl = -expf(tdc + acc[t]);
    wl = fmaxf(wl, -5.0f);
    float gg = expf(wl);
    size_t idx = (size_t)(tok0 + t) * Cz + c;
    g[idx] = gg;
    ksc[idx] = 1.f - gg;
  }
}

// ---------------------------------------------------------------------------
// m97-style bf16 MFMA GEMM: out[M=1024][N=2048] = A[M][K=2048] @ Wt[N][K]^T
// 128x128 block tile, BK=32, 4 waves 2x2, per-wave 4x4 of 16x16x32 MFMA.
__device__ __forceinline__ void gemm_tile(
    const bf16* __restrict__ A, const bf16* __restrict__ Wt,
    const float* __restrict__ bias, const float* __restrict__ kscale,
    float scl, float* __restrict__ out, int bM, int bN) {
  constexpr int K = Cz, N = Cz;
  __shared__ alignas(16) bf16 As[128 * 32];
  __shared__ alignas(16) bf16 Bs[128 * 32];
  int tid = threadIdx.x;
  int lane = tid & 63, wave = tid >> 6;
  int wm = wave & 1, wn = wave >> 1;

  f32x4 acc[4][4];
#pragma unroll
  for (int i = 0; i < 4; i++)
#pragma unroll
    for (int j = 0; j < 4; j++) acc[i][j] = (f32x4){0.f, 0.f, 0.f, 0.f};

  // staging: per wave, 16 rows x 64B per issue; 2 issues per matrix
  int srow = lane >> 2;
  int scol = (lane & 3) * 8;  // bf16 elements
  const bf16* gA = A + (size_t)(bM * 128 + wave * 16 + srow) * K + scol;
  const bf16* gB = Wt + (size_t)(bN * 128 + wave * 16 + srow) * K + scol;
  bf16* lA = As + (wave * 16) * 32;  // wave-uniform LDS base
  bf16* lB = Bs + (wave * 16) * 32;

  // fragment read addresses
  int fr = lane & 15, fk = (lane >> 4) * 8;
  const bf16* rA = As + (wm * 64 + fr) * 32 + fk;
  const bf16* rB = Bs + (wn * 64 + fr) * 32 + fk;

  for (int k0 = 0; k0 < K; k0 += 32) {
    load_lds16(gA + k0, lA);
    load_lds16(gA + (size_t)64 * K + k0, lA + 64 * 32);
    load_lds16(gB + k0, lB);
    load_lds16(gB + (size_t)64 * K + k0, lB + 64 * 32);
    __syncthreads();
    short8 af[4], bf[4];
#pragma unroll
    for (int i = 0; i < 4; i++) af[i] = *(const short8*)(rA + i * 16 * 32);
#pragma unroll
    for (int j = 0; j < 4; j++) bf[j] = *(const short8*)(rB + j * 16 * 32);
#pragma unroll
    for (int i = 0; i < 4; i++)
#pragma unroll
      for (int j = 0; j < 4; j++)
        acc[i][j] = __builtin_amdgcn_mfma_f32_16x16x32_bf16(af[i], bf[j],
                                                            acc[i][j], 0, 0, 0);
    __syncthreads();
  }

  // epilogue: C/D layout col = lane&15, row = (lane>>4)*4 + reg
  int r0 = (lane >> 4) * 4;
  int cn = lane & 15;
#pragma unroll
  for (int i = 0; i < 4; i++) {
    int mbase = bM * 128 + wm * 64 + i * 16 + r0;
#pragma unroll
    for (int j = 0; j < 4; j++) {
      int n = bN * 128 + wn * 64 + j * 16 + cn;
      float bv = bias ? bias[n] : 0.f;
#pragma unroll
      for (int r = 0; r < 4; r++) {
        float vv = (acc[i][j][r] + bv) * scl;
        size_t oi = (size_t)(mbase + r) * N + n;
        if (kscale) vv *= kscale[oi];
        out[oi] = vv;
      }
    }
  }
}

__global__ __launch_bounds__(256) void k_gemm_qkv(
    const bf16* __restrict__ xr, const bf16* __restrict__ xk,
    const bf16* __restrict__ xv, const bf16* __restrict__ qwt,
    const bf16* __restrict__ kwt, const bf16* __restrict__ vwt,
    const float* __restrict__ qb, const float* __restrict__ kb,
    const float* __restrict__ vb, const float* __restrict__ kscl,
    float* __restrict__ q, float* __restrict__ k, float* __restrict__ v) {
  const bf16 *A, *W;
  const float* b;
  const float* ks = nullptr;
  float* o;
  float scl = 1.f;
  if (blockIdx.z == 0) {
    A = xr; W = qwt; b = qb; o = q; scl = 0.125f;  // fold Dh^-0.5 into q
  } else if (blockIdx.z == 1) {
    A = xk; W = kwt; b = kb; o = k; ks = kscl;
  } else {
    A = xv; W = vwt; b = vb; o = v;
  }
  gemm_tile(A, W, b, ks, scl, o, blockIdx.y, blockIdx.x);
}

__global__ __launch_bounds__(256) void k_gemm_o(
    const bf16* __restrict__ yb, const bf16* __restrict__ owt,
    float* __restrict__ out) {
  gemm_tile(yb, owt, nullptr, nullptr, 1.f, out, blockIdx.y, blockIdx.x);
}

// ---------------------------------------------------------------------------
// GLA scan. One block per (b,h). 256 threads: wave g owns S rows
// [16g,16g+16), thread j (=lane) owns column j. 8 steps per barrier-phase.
__global__ __launch_bounds__(256) void k_scan(
    const float* __restrict__ q, const float* __restrict__ k,
    const float* __restrict__ v, const float* __restrict__ g,
    float* __restrict__ y) {
  __shared__ alignas(16) float sQ[8][64];
  __shared__ alignas(16) float sK[8][64];
  __shared__ alignas(16) float sG[8][64];
  __shared__ alignas(16) float sV[8][64];
  __shared__ float sR[8][4][64];
  int tid = threadIdx.x;
  int blk = blockIdx.x;
  int b = blk >> 5, h = blk & 31;
  int grp = tid >> 6, j = tid & 63;
  float S[16];
#pragma unroll
  for (int i = 0; i < 16; i++) S[i] = 0.f;
  size_t base = (size_t)b * Tz * Cz + h * 64;

  for (int p = 0; p < Tz / 8; p++) {
    // stage 8 steps of q,k,g,v
#pragma unroll
    for (int u = 0; u < 2; u++) {
      int idx = tid + 256 * u;
      int tt = idx >> 6, cc = idx & 63;
      size_t gi = base + (size_t)(p * 8 + tt) * Cz + cc;
      sQ[tt][cc] = q[gi];
      sK[tt][cc] = k[gi];
      sG[tt][cc] = g[gi];
      sV[tt][cc] = v[gi];
    }
    __syncthreads();
#pragma unroll
    for (int t = 0; t < 8; t++) {
      float vj = sV[t][j];
      float acc = 0.f;
#pragma unroll
      for (int i4 = 0; i4 < 4; i4++) {
        float4 g4 = *(const float4*)&sG[t][grp * 16 + i4 * 4];
        float4 k4 = *(const float4*)&sK[t][grp * 16 + i4 * 4];
        float4 q4 = *(const float4*)&sQ[t][grp * 16 + i4 * 4];
        int s0 = i4 * 4;
        S[s0 + 0] = S[s0 + 0] * g4.x + k4.x * vj; acc += q4.x * S[s0 + 0];
        S[s0 + 1] = S[s0 + 1] * g4.y + k4.y * vj; acc += q4.y * S[s0 + 1];
        S[s0 + 2] = S[s0 + 2] * g4.z + k4.z * vj; acc += q4.z * S[s0 + 2];
        S[s0 + 3] = S[s0 + 3] * g4.w + k4.w * vj; acc += q4.w * S[s0 + 3];
      }
      sR[t][grp][j] = acc;
    }
    __syncthreads();
    // reduce partials over the 4 groups and store y (q already scaled)
#pragma unroll
    for (int u = 0; u < 2; u++) {
      int idx = tid + 256 * u;
      int tt = idx >> 6, cc = idx & 63;
      float o = sR[tt][0][cc] + sR[tt][1][cc] + sR[tt][2][cc] + sR[tt][3][cc];
      y[base + (size_t)(p * 8 + tt) * Cz + cc] = o;
    }
  }
}

// ---------------------------------------------------------------------------
// LayerNorm over C, write bf16
__global__ __launch_bounds__(256) void k_ln(
    const float* __restrict__ y, const float* __restrict__ lg,
    const float* __restrict__ lb, bf16* __restrict__ yb) {
  __shared__ float red[8];
  int t = blockIdx.x;
  int tid = threadIdx.x;
  const float4* y4 = (const float4*)(y + (size_t)t * Cz);
  float4 vals[2];
  float s = 0.f, s2 = 0.f;
#pragma unroll
  for (int u = 0; u < 2; u++) {
    float4 a = y4[tid + 256 * u];
    vals[u] = a;
    s += a.x + a.y + a.z + a.w;
    s2 += a.x * a.x + a.y * a.y + a.z * a.z + a.w * a.w;
  }
#pragma unroll
  for (int off = 32; off > 0; off >>= 1) {
    s += __shfl_down(s, off);
    s2 += __shfl_down(s2, off);
  }
  if ((tid & 63) == 0) {
    red[(tid >> 6) * 2] = s;
    red[(tid >> 6) * 2 + 1] = s2;
  }
  __syncthreads();
  float ts = red[0] + red[2] + red[4] + red[6];
  float ts2 = red[1] + red[3] + red[5] + red[7];
  float mu = ts / (float)Cz;
  float var = ts2 / (float)Cz - mu * mu;
  float inv = rsqrtf(var + 1e-5f);
  bf16* outp = yb + (size_t)t * Cz;
#pragma unroll
  for (int u = 0; u < 2; u++) {
    int c0 = (tid + 256 * u) * 4;
    float4 a = vals[u];
    outp[c0 + 0] = __float2bfloat16((a.x - mu) * inv * lg[c0 + 0] + lb[c0 + 0]);
    outp[c0 + 1] = __float2bfloat16((a.y - mu) * inv * lg[c0 + 1] + lb[c0 + 1]);
    outp[c0 + 2] = __float2bfloat16((a.z - mu) * inv * lg[c0 + 2] + lb[c0 + 2]);
    outp[c0 + 3] = __float2bfloat16((a.w - mu) * inv * lg[c0 + 3] + lb[c0 + 3]);
  }
}

// ---------------------------------------------------------------------------
extern "C" void kernel_launch(void* const* d_in, const int* in_sizes, int n_in,
                              void* d_out, int out_size, void* d_ws,
                              size_t ws_size, hipStream_t stream) {
  const float* x      = (const float*)d_in[0];
  const float* maa_x  = (const float*)d_in[1];
  const float* maa_r  = (const float*)d_in[2];
  const float* maa_k  = (const float*)d_in[3];
  const float* maa_v  = (const float*)d_in[4];
  const float* maa_w  = (const float*)d_in[5];
  const float* maa_w1 = (const float*)d_in[6];
  const float* maa_w2 = (const float*)d_in[7];
  const float* tdcay  = (const float*)d_in[8];
  const float* td_w1  = (const float*)d_in[9];
  const float* td_w2  = (const float*)d_in[10];
  const float* q_w    = (const float*)d_in[11];
  const float* q_b    = (const float*)d_in[12];
  const float* k_w    = (const float*)d_in[13];
  const float* k_b    = (const float*)d_in[14];
  const float* v_w    = (const float*)d_in[15];
  const float* v_b    = (const float*)d_in[16];
  const float* ln_g   = (const float*)d_in[17];
  const float* ln_b   = (const float*)d_in[18];
  const float* o_w    = (const float*)d_in[19];
  float* out = (float*)d_out;

  char* p = (char*)d_ws;
  auto alloc = [&](size_t bytes) {
    char* r = p;
    p += (bytes + 255) & ~(size_t)255;
    return r;
  };
  const size_t WB = (size_t)Cz * Cz * sizeof(bf16);   // 8 MB
  const size_t AF = (size_t)NTOK * Cz * sizeof(float); // 8 MB
  const size_t AB = (size_t)NTOK * Cz * sizeof(bf16);  // 4 MB

  bf16* qwt = (bf16*)alloc(WB);
  bf16* kwt = (bf16*)alloc(WB);
  bf16* vwt = (bf16*)alloc(WB);
  bf16* owt = (bf16*)alloc(WB);
  float* dx  = (float*)alloc(AF);
  float* xxx = (float*)alloc(AF);
  float* mm  = (float*)alloc((size_t)NTOK * 128 * sizeof(float));
  bf16* xr = (bf16*)alloc(AB);
  bf16* xk = (bf16*)alloc(AB);
  bf16* xv = (bf16*)alloc(AB);
  float* xw = (float*)alloc(AF);
  float* tw = (float*)alloc((size_t)NTOK * 64 * sizeof(float));
  float* gdecay = (float*)alloc(AF);
  float* kscl   = (float*)alloc(AF);
  float* q = (float*)alloc(AF);
  float* k = (float*)alloc(AF);
  float* v = (float*)alloc(AF);
  float* y = (float*)alloc(AF);
  bf16* yb = (bf16*)alloc(AB);

  // 1. weight transpose+convert (independent of everything else)
  k_transpose<<<dim3(64, 64, 4), dim3(32, 8), 0, stream>>>(
      q_w, k_w, v_w, o_w, qwt, kwt, vwt, owt);
  // 2. token shift
  k_prep<<<2048, 256, 0, stream>>>(x, maa_x, dx, xxx);
  // 3. mix LoRA stage 1
  k_mm<<<128, 256, 0, stream>>>(xxx, maa_w1, mm);
  // 4. mix LoRA stage 2 + fused xr/xk/xv/xw
  k_mproj<<<dim3(128, 8), 256, 0, stream>>>(mm, maa_w2, x, dx, maa_r, maa_k,
                                            maa_v, maa_w, xr, xk, xv, xw);
  // 5-6. decay LoRA
  k_tdA<<<128, 256, 0, stream>>>(xw, td_w1, tw);
  k_tdB<<<dim3(128, 8), 256, 0, stream>>>(tw, td_w2, tdcay, gdecay, kscl);
  // 7. q,k,v projections (fused; k scaled by 1-g, q scaled by Dh^-0.5)
  k_gemm_qkv<<<dim3(16, 8, 3), 256, 0, stream>>>(
      xr, xk, xv, qwt, kwt, vwt, q_b, k_b, v_b, kscl, q, k, v);
  // 8. GLA scan
  k_scan<<<Bz * Hh, 256, 0, stream>>>(q, k, v, gdecay, y);
  // 9. LayerNorm -> bf16
  k_ln<<<NTOK, 256, 0, stream>>>(y, ln_g, ln_b, yb);
  // 10. output projection
  k_gemm_o<<<dim3(16, 8, 1), 256, 0, stream>>>(yb, owt, out);
}

// Round 2
// 541.220 us; speedup vs baseline: 1.2700x; 1.2700x over previous
//
#include <hip/hip_runtime.h>
#include <hip/hip_bf16.h>
#include <math.h>

// Problem constants
#define Bz 2
#define Tz 512
#define Cz 2048
#define Hh 32
#define DH 64
#define NTOK (Bz * Tz)   // 1024
#define NCH 8            // chunks per sequence (Tz/64)

typedef __hip_bfloat16 bf16;
typedef __attribute__((ext_vector_type(8))) short short8;
typedef __attribute__((ext_vector_type(4))) float f32x4;

// ---------------------------------------------------------------------------
// async global->LDS, 16B per lane. LDS dest must be wave-uniform base;
// lanes land at base + lane*16.
__device__ __forceinline__ void load_lds16(const void* g, void* l) {
  __builtin_amdgcn_global_load_lds(
      (const __attribute__((address_space(1))) unsigned int*)g,
      (__attribute__((address_space(3))) unsigned int*)l,
      16, 0, 0);
}

// ---------------------------------------------------------------------------
// Weight transpose + f32->bf16: Wt[n][k] = (bf16) W[k][n].  z selects weight.
__global__ __launch_bounds__(256) void k_transpose(
    const float* __restrict__ qw, const float* __restrict__ kw,
    const float* __restrict__ vw, const float* __restrict__ ow,
    bf16* __restrict__ qwt, bf16* __restrict__ kwt,
    bf16* __restrict__ vwt, bf16* __restrict__ owt) {
  __shared__ float tile[32][33];
  const float* W;
  bf16* O;
  switch (blockIdx.z) {
    case 0: W = qw; O = qwt; break;
    case 1: W = kw; O = kwt; break;
    case 2: W = vw; O = vwt; break;
    default: W = ow; O = owt; break;
  }
  int bx = blockIdx.x * 32, by = blockIdx.y * 32;
  int tx = threadIdx.x, ty = threadIdx.y;
#pragma unroll
  for (int i = 0; i < 4; i++)
    tile[ty + 8 * i][tx] = W[(size_t)(by + ty + 8 * i) * Cz + bx + tx];
  __syncthreads();
#pragma unroll
  for (int i = 0; i < 4; i++)
    O[(size_t)(bx + ty + 8 * i) * Cz + by + tx] =
        __float2bfloat16(tile[tx][ty + 8 * i]);
}

// ---------------------------------------------------------------------------
// dx = x_{t-1} - x_t (zero pad at t=0);  xxx = x + dx*maa_x
__global__ __launch_bounds__(256) void k_prep(
    const float* __restrict__ x, const float* __restrict__ maa_x,
    float* __restrict__ dx, float* __restrict__ xxx) {
  int i4 = blockIdx.x * 256 + threadIdx.x;  // over 524288 float4
  int row = i4 >> 9;                        // 512 float4 per row
  int t = row & (Tz - 1);
  int c4 = i4 & 511;
  const float4* x4 = (const float4*)x;
  float4 xv = x4[i4];
  float4 xp = make_float4(0.f, 0.f, 0.f, 0.f);
  if (t != 0) xp = x4[i4 - 512];
  float4 mx = ((const float4*)maa_x)[c4];
  float4 d, xx;
  d.x = xp.x - xv.x; d.y = xp.y - xv.y; d.z = xp.z - xv.z; d.w = xp.w - xv.w;
  xx.x = xv.x + d.x * mx.x; xx.y = xv.y + d.y * mx.y;
  xx.z = xv.z + d.z * mx.z; xx.w = xv.w + d.w * mx.w;
  ((float4*)dx)[i4] = d;
  ((float4*)xxx)[i4] = xx;
}

// ---------------------------------------------------------------------------
// mm = tanh(xxx @ maa_w1)   [NTOK,128], 8 tokens per block
__global__ __launch_bounds__(256) void k_mm(
    const float* __restrict__ xxx, const float* __restrict__ w1,
    float* __restrict__ mm) {
  __shared__ float sX[8][64];
  int tid = threadIdx.x;
  int o = tid & 127, tg = tid >> 7;  // 2 token-groups of 4
  int tok0 = blockIdx.x * 8;
  float acc[4] = {0.f, 0.f, 0.f, 0.f};
  for (int kc = 0; kc < Cz; kc += 64) {
#pragma unroll
    for (int u = 0; u < 2; u++) {
      int idx = tid + 256 * u;
      sX[idx >> 6][idx & 63] = xxx[(size_t)(tok0 + (idx >> 6)) * Cz + kc + (idx & 63)];
    }
    __syncthreads();
    for (int c = 0; c < 64; c++) {
      float w = w1[(size_t)(kc + c) * 128 + o];
#pragma unroll
      for (int t = 0; t < 4; t++) acc[t] += w * sX[tg * 4 + t][c];
    }
    __syncthreads();
  }
#pragma unroll
  for (int t = 0; t < 4; t++)
    mm[(size_t)(tok0 + tg * 4 + t) * 128 + o] = tanhf(acc[t]);
}

// ---------------------------------------------------------------------------
// m_r = mm @ maa_w2[r]; fuse xr/xk/xv (bf16) and xw (f32) outputs.
// grid: (NTOK/8, Cz/256), block 256.
__global__ __launch_bounds__(256) void k_mproj(
    const float* __restrict__ mm, const float* __restrict__ w2,
    const float* __restrict__ x, const float* __restrict__ dx,
    const float* __restrict__ maa_r, const float* __restrict__ maa_k,
    const float* __restrict__ maa_v, const float* __restrict__ maa_w,
    bf16* __restrict__ pxr, bf16* __restrict__ pxk,
    bf16* __restrict__ pxv, float* __restrict__ pxw) {
  __shared__ float sM[8][128];
  int tid = threadIdx.x;
  int tok0 = blockIdx.x * 8;
  int c = blockIdx.y * 256 + tid;
#pragma unroll
  for (int u = 0; u < 4; u++) {
    int idx = tid + 256 * u;
    sM[idx >> 7][idx & 127] = mm[(size_t)tok0 * 128 + idx];
  }
  __syncthreads();
  float m_[4][8];
#pragma unroll
  for (int r = 0; r < 4; r++)
#pragma unroll
    for (int t = 0; t < 8; t++) m_[r][t] = 0.f;
#pragma unroll
  for (int r = 0; r < 4; r++) {
    for (int d = 0; d < 32; d++) {
      float w = w2[(size_t)(r * 32 + d) * Cz + c];
#pragma unroll
      for (int t = 0; t < 8; t++) m_[r][t] += w * sM[t][r * 32 + d];
    }
  }
  float mr = maa_r[c], mk = maa_k[c], mv = maa_v[c], mw = maa_w[c];
#pragma unroll
  for (int t = 0; t < 8; t++) {
    size_t idx = (size_t)(tok0 + t) * Cz + c;
    float xval = x[idx], dval = dx[idx];
    pxr[idx] = __float2bfloat16(xval + dval * (mr + m_[0][t]));
    pxk[idx] = __float2bfloat16(xval + dval * (mk + m_[1][t]));
    pxv[idx] = __float2bfloat16(xval + dval * (mv + m_[2][t]));
    pxw[idx] = xval + dval * (mw + m_[3][t]);
  }
}

// ---------------------------------------------------------------------------
// tw = tanh(xw @ td_w1)  [NTOK,64], 8 tokens per block
__global__ __launch_bounds__(256) void k_tdA(
    const float* __restrict__ xw, const float* __restrict__ w1,
    float* __restrict__ tw) {
  __shared__ float sX[8][64];
  int tid = threadIdx.x;
  int o = tid & 63, tg = tid >> 6;  // 4 groups of 2 tokens
  int tok0 = blockIdx.x * 8;
  float acc0 = 0.f, acc1 = 0.f;
  for (int kc = 0; kc < Cz; kc += 64) {
#pragma unroll
    for (int u = 0; u < 2; u++) {
      int idx = tid + 256 * u;
      sX[idx >> 6][idx & 63] = xw[(size_t)(tok0 + (idx >> 6)) * Cz + kc + (idx & 63)];
    }
    __syncthreads();
    for (int cc = 0; cc < 64; cc++) {
      float w = w1[(size_t)(kc + cc) * 64 + o];
      acc0 += w * sX[tg * 2][cc];
      acc1 += w * sX[tg * 2 + 1][cc];
    }
    __syncthreads();
  }
  tw[(size_t)(tok0 + tg * 2) * 64 + o] = tanhf(acc0);
  tw[(size_t)(tok0 + tg * 2 + 1) * 64 + o] = tanhf(acc1);
}

// ---------------------------------------------------------------------------
// w_log = max(-exp(td + tw @ td_w2), -5); write wlog (f32) and ksc = 1-exp(wlog)
// grid: (NTOK/8, Cz/256)
__global__ __launch_bounds__(256) void k_tdB(
    const float* __restrict__ tw, const float* __restrict__ w2,
    const float* __restrict__ td, float* __restrict__ wlog,
    float* __restrict__ ksc) {
  __shared__ float sT[8][64];
  int tid = threadIdx.x;
  int tok0 = blockIdx.x * 8;
  int c = blockIdx.y * 256 + tid;
#pragma unroll
  for (int u = 0; u < 2; u++) {
    int idx = tid + 256 * u;
    sT[idx >> 6][idx & 63] = tw[(size_t)tok0 * 64 + idx];
  }
  __syncthreads();
  float acc[8];
#pragma unroll
  for (int t = 0; t < 8; t++) acc[t] = 0.f;
  for (int d = 0; d < 64; d++) {
    float w = w2[(size_t)d * Cz + c];
#pragma unroll
    for (int t = 0; t < 8; t++) acc[t] += w * sT[t][d];
  }
  float tdc = td[c];
#pragma unroll
  for (int t = 0; t < 8; t++) {
    float wl = -expf(tdc + acc[t]);
    wl = fmaxf(wl, -5.0f);
    size_t idx = (size_t)(tok0 + t) * Cz + c;
    wlog[idx] = wl;
    ksc[idx] = 1.f - expf(wl);
  }
}

// ---------------------------------------------------------------------------
// m97-style bf16 MFMA GEMM: out[M=1024][N=2048] = A[M][K=2048] @ Wt[N][K]^T
__device__ __forceinline__ void gemm_tile(
    const bf16* __restrict__ A, const bf16* __restrict__ Wt,
    const float* __restrict__ bias, const float* __restrict__ kscale,
    float scl, float* __restrict__ out, int bM, int bN) {
  constexpr int K = Cz, N = Cz;
  __shared__ alignas(16) bf16 As[128 * 32];
  __shared__ alignas(16) bf16 Bs[128 * 32];
  int tid = threadIdx.x;
  int lane = tid & 63, wave = tid >> 6;
  int wm = wave & 1, wn = wave >> 1;

  f32x4 acc[4][4];
#pragma unroll
  for (int i = 0; i < 4; i++)
#pragma unroll
    for (int j = 0; j < 4; j++) acc[i][j] = (f32x4){0.f, 0.f, 0.f, 0.f};

  int srow = lane >> 2;
  int scol = (lane & 3) * 8;
  const bf16* gA = A + (size_t)(bM * 128 + wave * 16 + srow) * K + scol;
  const bf16* gB = Wt + (size_t)(bN * 128 + wave * 16 + srow) * K + scol;
  bf16* lA = As + (wave * 16) * 32;
  bf16* lB = Bs + (wave * 16) * 32;

  int fr = lane & 15, fk = (lane >> 4) * 8;
  const bf16* rA = As + (wm * 64 + fr) * 32 + fk;
  const bf16* rB = Bs + (wn * 64 + fr) * 32 + fk;

  for (int k0 = 0; k0 < K; k0 += 32) {
    load_lds16(gA + k0, lA);
    load_lds16(gA + (size_t)64 * K + k0, lA + 64 * 32);
    load_lds16(gB + k0, lB);
    load_lds16(gB + (size_t)64 * K + k0, lB + 64 * 32);
    __syncthreads();
    short8 af[4], bf[4];
#pragma unroll
    for (int i = 0; i < 4; i++) af[i] = *(const short8*)(rA + i * 16 * 32);
#pragma unroll
    for (int j = 0; j < 4; j++) bf[j] = *(const short8*)(rB + j * 16 * 32);
#pragma unroll
    for (int i = 0; i < 4; i++)
#pragma unroll
      for (int j = 0; j < 4; j++)
        acc[i][j] = __builtin_amdgcn_mfma_f32_16x16x32_bf16(af[i], bf[j],
                                                            acc[i][j], 0, 0, 0);
    __syncthreads();
  }

  int r0 = (lane >> 4) * 4;
  int cn = lane & 15;
#pragma unroll
  for (int i = 0; i < 4; i++) {
    int mbase = bM * 128 + wm * 64 + i * 16 + r0;
#pragma unroll
    for (int j = 0; j < 4; j++) {
      int n = bN * 128 + wn * 64 + j * 16 + cn;
      float bv = bias ? bias[n] : 0.f;
#pragma unroll
      for (int r = 0; r < 4; r++) {
        float vv = (acc[i][j][r] + bv) * scl;
        size_t oi = (size_t)(mbase + r) * N + n;
        if (kscale) vv *= kscale[oi];
        out[oi] = vv;
      }
    }
  }
}

__global__ __launch_bounds__(256) void k_gemm_qkv(
    const bf16* __restrict__ xr, const bf16* __restrict__ xk,
    const bf16* __restrict__ xv, const bf16* __restrict__ qwt,
    const bf16* __restrict__ kwt, const bf16* __restrict__ vwt,
    const float* __restrict__ qb, const float* __restrict__ kb,
    const float* __restrict__ vb, const float* __restrict__ kscl,
    float* __restrict__ q, float* __restrict__ k, float* __restrict__ v) {
  const bf16 *A, *W;
  const float* b;
  const float* ks = nullptr;
  float* o;
  float scl = 1.f;
  if (blockIdx.z == 0) {
    A = xr; W = qwt; b = qb; o = q; scl = 0.125f;  // fold Dh^-0.5 into q
  } else if (blockIdx.z == 1) {
    A = xk; W = kwt; b = kb; o = k; ks = kscl;
  } else {
    A = xv; W = vwt; b = vb; o = v;
  }
  gemm_tile(A, W, b, ks, scl, o, blockIdx.y, blockIdx.x);
}

__global__ __launch_bounds__(256) void k_gemm_o(
    const bf16* __restrict__ yb, const bf16* __restrict__ owt,
    float* __restrict__ out) {
  gemm_tile(yb, owt, nullptr, nullptr, 1.f, out, blockIdx.y, blockIdx.x);
}

// ---------------------------------------------------------------------------
// Chunked GLA pass 1: per (b,h,chunk of 64): cumsum of wlog; emit
// qt = q*exp(cum), kt = k*exp(-cum), kh = k*exp(cumL-cum) (bf16, chunk-major),
// aL[d] = exp(cumL), and U[d][j] = sum_s kh[s][d]*v[s][j].
__global__ __launch_bounds__(256) void k_chunk_prep(
    const float* __restrict__ q, const float* __restrict__ k,
    const float* __restrict__ v, const float* __restrict__ wlog,
    bf16* __restrict__ qt, bf16* __restrict__ kt, bf16* __restrict__ kh,
    float* __restrict__ aL, float* __restrict__ U) {
  __shared__ float sCum[64 * 64];
  __shared__ float sKh[64 * 64];
  __shared__ float sV[64 * 64];
  int tid = threadIdx.x;
  int bhc = blockIdx.x;
  int c = bhc & 7, h = (bhc >> 3) & 31, b = bhc >> 8;
  size_t gbase = ((size_t)(b * Tz) + c * 64) * Cz + h * 64;
  size_t cbase = (size_t)bhc * 4096;

  // load wlog, k, v (float4)
#pragma unroll
  for (int i = 0; i < 4; i++) {
    int i4 = tid + i * 256;           // 1024 float4
    int t = i4 >> 4, dq = i4 & 15;
    size_t g = gbase + (size_t)t * Cz + dq * 4;
    *(float4*)&sCum[t * 64 + dq * 4] = *(const float4*)&wlog[g];
    *(float4*)&sKh[t * 64 + dq * 4] = *(const float4*)&k[g];
    *(float4*)&sV[t * 64 + dq * 4] = *(const float4*)&v[g];
  }
  __syncthreads();
  // inclusive cumsum over t (lane d)
  if (tid < 64) {
    float cum = 0.f;
#pragma unroll
    for (int t = 0; t < 64; t++) {
      cum += sCum[t * 64 + tid];
      sCum[t * 64 + tid] = cum;
    }
  }
  __syncthreads();
  // scale & emit; overwrite sKh with K-hat (f32)
#pragma unroll
  for (int i = 0; i < 16; i++) {
    int idx = tid + i * 256;
    int t = idx >> 6, d = idx & 63;
    float cl = sCum[t * 64 + d];
    float cL = sCum[63 * 64 + d];
    float kraw = sKh[t * 64 + d];
    float qv = q[gbase + (size_t)t * Cz + d];
    float khv = kraw * expf(cL - cl);
    qt[cbase + idx] = __float2bfloat16(qv * expf(cl));
    kt[cbase + idx] = __float2bfloat16(kraw * expf(-cl));
    kh[cbase + idx] = __float2bfloat16(khv);
    sKh[t * 64 + d] = khv;
    if (t == 63) aL[(size_t)bhc * 64 + d] = expf(cl);
  }
  __syncthreads();
  // U[d][j] = sum_s Kh[s][d] * V[s][j]; thread (j=tid&63, dg=tid>>6)
  int j = tid & 63, dg = tid >> 6;
  float acc[16];
#pragma unroll
  for (int dd = 0; dd < 16; dd++) acc[dd] = 0.f;
  for (int s = 0; s < 64; s++) {
    float vs = sV[s * 64 + j];
#pragma unroll
    for (int dd = 0; dd < 16; dd++)
      acc[dd] += sKh[s * 64 + dg * 16 + dd] * vs;
  }
#pragma unroll
  for (int dd = 0; dd < 16; dd++)
    U[cbase + (size_t)(dg * 16 + dd) * 64 + j] = acc[dd];
}

// ---------------------------------------------------------------------------
// Chunked GLA pass 2 (sequential over 8 chunks): S_{c+1} = diag(aL)*S_c + U_c.
// Stores carry-in state per chunk. grid: 64 bh * 4 jg = 256 blocks, 64 thr.
__global__ __launch_bounds__(64) void k_carry(
    const float* __restrict__ aL, const float* __restrict__ U,
    float* __restrict__ Sc) {
  int bh = blockIdx.x >> 2;
  int jg = blockIdx.x & 3;
  int tid = threadIdx.x;
  int jj = tid & 15, dg = tid >> 4;
  int j = jg * 16 + jj;
  float S[16];
#pragma unroll
  for (int dd = 0; dd < 16; dd++) S[dd] = 0.f;
  for (int c = 0; c < NCH; c++) {
    int bhc = bh * NCH + c;
    size_t base = (size_t)bhc * 4096;
#pragma unroll
    for (int dd = 0; dd < 16; dd++) {
      int d = dg * 16 + dd;
      Sc[base + (size_t)d * 64 + j] = S[dd];
      S[dd] = S[dd] * aL[(size_t)bhc * 64 + d] + U[base + (size_t)d * 64 + j];
    }
  }
}

// ---------------------------------------------------------------------------
// Chunked GLA pass 3: o = mask(qt @ kt^T) @ V + qt @ S_c.  512 blocks.
__global__ __launch_bounds__(256) void k_chunk_out(
    const bf16* __restrict__ qt, const bf16* __restrict__ kt,
    const float* __restrict__ v, const float* __restrict__ Sc,
    float* __restrict__ y) {
  __shared__ float sQ[64 * 65];
  __shared__ float sKS[64 * 65];  // k-tilde (stride 65), later S (stride 64)
  __shared__ float sP[64 * 65];
  __shared__ float sV[64 * 64];
  int tid = threadIdx.x;
  int bhc = blockIdx.x;
  int c = bhc & 7, h = (bhc >> 3) & 31, b = bhc >> 8;
  size_t gbase = ((size_t)(b * Tz) + c * 64) * Cz + h * 64;
  size_t cbase = (size_t)bhc * 4096;

  // load qt, kt (bf16 -> f32, stride 65)
#pragma unroll
  for (int i = 0; i < 4; i++) {
    int i4 = tid + i * 256;  // 1024 quads
    int t = i4 >> 4, dq = i4 & 15;
    ushort4 qu = *(const ushort4*)&qt[cbase + i4 * 4];
    ushort4 ku = *(const ushort4*)&kt[cbase + i4 * 4];
    float* dstq = &sQ[t * 65 + dq * 4];
    float* dstk = &sKS[t * 65 + dq * 4];
    unsigned int uq[4] = {qu.x, qu.y, qu.z, qu.w};
    unsigned int uk[4] = {ku.x, ku.y, ku.z, ku.w};
#pragma unroll
    for (int e = 0; e < 4; e++) {
      unsigned int bq = uq[e] << 16;
      unsigned int bk = uk[e] << 16;
      dstq[e] = __builtin_bit_cast(float, bq);
      dstk[e] = __builtin_bit_cast(float, bk);
    }
  }
  __syncthreads();
  // P[t][s] = sum_d qt[t][d]*kt[s][d], causal mask s<=t
  int tg = tid & 15, sg = tid >> 4;
  float p[4][4];
#pragma unroll
  for (int i = 0; i < 4; i++)
#pragma unroll
    for (int jx = 0; jx < 4; jx++) p[i][jx] = 0.f;
  for (int d = 0; d < 64; d++) {
    float qv[4], kv[4];
#pragma unroll
    for (int i = 0; i < 4; i++) qv[i] = sQ[(tg * 4 + i) * 65 + d];
#pragma unroll
    for (int jx = 0; jx < 4; jx++) kv[jx] = sKS[(sg * 4 + jx) * 65 + d];
#pragma unroll
    for (int i = 0; i < 4; i++)
#pragma unroll
      for (int jx = 0; jx < 4; jx++) p[i][jx] += qv[i] * kv[jx];
  }
#pragma unroll
  for (int i = 0; i < 4; i++) {
    int t = tg * 4 + i;
#pragma unroll
    for (int jx = 0; jx < 4; jx++) {
      int s = sg * 4 + jx;
      sP[t * 65 + s] = (s <= t) ? p[i][jx] : 0.f;
    }
  }
  __syncthreads();
  // load S (stride 64, overwrites kt) and V
#pragma unroll
  for (int i = 0; i < 4; i++) {
    int i4 = tid + i * 256;
    int t = i4 >> 4, dq = i4 & 15;
    *(float4*)&sKS[t * 64 + dq * 4] = *(const float4*)&Sc[cbase + i4 * 4];
    *(float4*)&sV[t * 64 + dq * 4] =
        *(const float4*)&v[gbase + (size_t)t * Cz + dq * 4];
  }
  __syncthreads();
  // o[t][j] = sum_s P[t][s] V[s][j] + sum_d qt[t][d] S[d][j]
  f32x4 o[4];
#pragma unroll
  for (int i = 0; i < 4; i++) o[i] = (f32x4){0.f, 0.f, 0.f, 0.f};
  for (int s = 0; s < 64; s++) {
    f32x4 vv = *(const f32x4*)&sV[s * 64 + sg * 4];
#pragma unroll
    for (int i = 0; i < 4; i++) {
      float pv = sP[(tg * 4 + i) * 65 + s];
      o[i] += pv * vv;
    }
  }
  for (int d = 0; d < 64; d++) {
    f32x4 sv = *(const f32x4*)&sKS[d * 64 + sg * 4];
#pragma unroll
    for (int i = 0; i < 4; i++) {
      float qv = sQ[(tg * 4 + i) * 65 + d];
      o[i] += qv * sv;
    }
  }
#pragma unroll
  for (int i = 0; i < 4; i++) {
    int t = tg * 4 + i;
    *(f32x4*)&y[gbase + (size_t)t * Cz + sg * 4] = o[i];
  }
}

// ---------------------------------------------------------------------------
// LayerNorm over C, write bf16
__global__ __launch_bounds__(256) void k_ln(
    const float* __restrict__ y, const float* __restrict__ lg,
    const float* __restrict__ lb, bf16* __restrict__ yb) {
  __shared__ float red[8];
  int t = blockIdx.x;
  int tid = threadIdx.x;
  const float4* y4 = (const float4*)(y + (size_t)t * Cz);
  float4 vals[2];
  float s = 0.f, s2 = 0.f;
#pragma unroll
  for (int u = 0; u < 2; u++) {
    float4 a = y4[tid + 256 * u];
    vals[u] = a;
    s += a.x + a.y + a.z + a.w;
    s2 += a.x * a.x + a.y * a.y + a.z * a.z + a.w * a.w;
  }
#pragma unroll
  for (int off = 32; off > 0; off >>= 1) {
    s += __shfl_down(s, off);
    s2 += __shfl_down(s2, off);
  }
  if ((tid & 63) == 0) {
    red[(tid >> 6) * 2] = s;
    red[(tid >> 6) * 2 + 1] = s2;
  }
  __syncthreads();
  float ts = red[0] + red[2] + red[4] + red[6];
  float ts2 = red[1] + red[3] + red[5] + red[7];
  float mu = ts / (float)Cz;
  float var = ts2 / (float)Cz - mu * mu;
  float inv = rsqrtf(var + 1e-5f);
  bf16* outp = yb + (size_t)t * Cz;
#pragma unroll
  for (int u = 0; u < 2; u++) {
    int c0 = (tid + 256 * u) * 4;
    float4 a = vals[u];
    outp[c0 + 0] = __float2bfloat16((a.x - mu) * inv * lg[c0 + 0] + lb[c0 + 0]);
    outp[c0 + 1] = __float2bfloat16((a.y - mu) * inv * lg[c0 + 1] + lb[c0 + 1]);
    outp[c0 + 2] = __float2bfloat16((a.z - mu) * inv * lg[c0 + 2] + lb[c0 + 2]);
    outp[c0 + 3] = __float2bfloat16((a.w - mu) * inv * lg[c0 + 3] + lb[c0 + 3]);
  }
}

// ---------------------------------------------------------------------------
extern "C" void kernel_launch(void* const* d_in, const int* in_sizes, int n_in,
                              void* d_out, int out_size, void* d_ws,
                              size_t ws_size, hipStream_t stream) {
  const float* x      = (const float*)d_in[0];
  const float* maa_x  = (const float*)d_in[1];
  const float* maa_r  = (const float*)d_in[2];
  const float* maa_k  = (const float*)d_in[3];
  const float* maa_v  = (const float*)d_in[4];
  const float* maa_w  = (const float*)d_in[5];
  const float* maa_w1 = (const float*)d_in[6];
  const float* maa_w2 = (const float*)d_in[7];
  const float* tdcay  = (const float*)d_in[8];
  const float* td_w1  = (const float*)d_in[9];
  const float* td_w2  = (const float*)d_in[10];
  const float* q_w    = (const float*)d_in[11];
  const float* q_b    = (const float*)d_in[12];
  const float* k_w    = (const float*)d_in[13];
  const float* k_b    = (const float*)d_in[14];
  const float* v_w    = (const float*)d_in[15];
  const float* v_b    = (const float*)d_in[16];
  const float* ln_g   = (const float*)d_in[17];
  const float* ln_b   = (const float*)d_in[18];
  const float* o_w    = (const float*)d_in[19];
  float* out = (float*)d_out;

  char* p = (char*)d_ws;
  auto alloc = [&](size_t bytes) {
    char* r = p;
    p += (bytes + 255) & ~(size_t)255;
    return r;
  };
  const size_t WB = (size_t)Cz * Cz * sizeof(bf16);    // 8 MB
  const size_t AF = (size_t)NTOK * Cz * sizeof(float); // 8 MB
  const size_t AB = (size_t)NTOK * Cz * sizeof(bf16);  // 4 MB

  bf16* qwt = (bf16*)alloc(WB);
  bf16* kwt = (bf16*)alloc(WB);
  bf16* vwt = (bf16*)alloc(WB);
  bf16* owt = (bf16*)alloc(WB);
  float* dx  = (float*)alloc(AF);
  float* xxx = (float*)alloc(AF);
  float* mm  = (float*)alloc((size_t)NTOK * 128 * sizeof(float));
  bf16* xr = (bf16*)alloc(AB);
  bf16* xk = (bf16*)alloc(AB);
  bf16* xv = (bf16*)alloc(AB);
  float* xw = (float*)alloc(AF);
  float* tw = (float*)alloc((size_t)NTOK * 64 * sizeof(float));
  float* wlog = (float*)alloc(AF);
  float* kscl = (float*)alloc(AF);
  float* q = (float*)alloc(AF);
  float* k = (float*)alloc(AF);
  float* v = (float*)alloc(AF);
  float* y = (float*)alloc(AF);
  bf16* yb = (bf16*)alloc(AB);

  // chunked-scan buffers reuse dead arrays (all within this launch):
  bf16* qt = (bf16*)xxx;            // 4 MB (xxx dead after k_mm)
  bf16* kt = (bf16*)((char*)xxx + 4 * 1024 * 1024);  // 4 MB
  bf16* kh = (bf16*)dx;             // 4 MB (dx dead after k_mproj)
  float* U = xw;                    // 8 MB (xw dead after k_tdA)
  float* aLbuf = mm;                // 128 KB (mm dead after k_mproj)
  float* Scar = q;                  // 8 MB (q dead after k_chunk_prep)

  // 1. weight transpose+convert
  k_transpose<<<dim3(64, 64, 4), dim3(32, 8), 0, stream>>>(
      q_w, k_w, v_w, o_w, qwt, kwt, vwt, owt);
  // 2. token shift
  k_prep<<<2048, 256, 0, stream>>>(x, maa_x, dx, xxx);
  // 3. mix LoRA stage 1
  k_mm<<<128, 256, 0, stream>>>(xxx, maa_w1, mm);
  // 4. mix LoRA stage 2 + fused xr/xk/xv/xw
  k_mproj<<<dim3(128, 8), 256, 0, stream>>>(mm, maa_w2, x, dx, maa_r, maa_k,
                                            maa_v, maa_w, xr, xk, xv, xw);
  // 5-6. decay LoRA
  k_tdA<<<128, 256, 0, stream>>>(xw, td_w1, tw);
  k_tdB<<<dim3(128, 8), 256, 0, stream>>>(tw, td_w2, tdcay, wlog, kscl);
  // 7. q,k,v projections (k scaled by 1-exp(wlog), q scaled by Dh^-0.5)
  k_gemm_qkv<<<dim3(16, 8, 3), 256, 0, stream>>>(
      xr, xk, xv, qwt, kwt, vwt, q_b, k_b, v_b, kscl, q, k, v);
  // 8. chunked GLA
  k_chunk_prep<<<512, 256, 0, stream>>>(q, k, v, wlog, qt, kt, kh, aLbuf, U);
  k_carry<<<256, 64, 0, stream>>>(aLbuf, U, Scar);
  k_chunk_out<<<512, 256, 0, stream>>>(qt, kt, v, Scar, y);
  // 9. LayerNorm -> bf16
  k_ln<<<NTOK, 256, 0, stream>>>(y, ln_g, ln_b, yb);
  // 10. output projection
  k_gemm_o<<<dim3(16, 8, 1), 256, 0, stream>>>(yb, owt, out);
}